// Round 6
// baseline (89.168 us; speedup 1.0000x reference)
//
#include <hip/hip_runtime.h>
#include <stdint.h>
#include <math.h>

typedef uint32_t u32;
typedef uint64_t u64;
typedef int32_t  i32;

#define BB 8
#define CAT 10
#define HW 262144             // 512*512
#define WW 512
#define KSEL 500
#define NWG 1024              // total workgroups
#define THREADS 256
#define EPW 20480             // elements per WG = BB*CAT*HW / NWG
#define WPB 128               // WGs per batch = EPW*? (2621440/20480)
#define LCAP 48               // per-WG candidate cap (mean 8.2, sigma 2.9 -> ~14 sigma)
#define CANDCAP 2048          // per-batch cap (mean 1049, sigma 32)
#define SLICES 16
#define RANKERS 128           // SLICES * BB
#define THRV 0.9996f
#define NB 4096               // fallback histogram buckets
#define NBQ 16                // NB / THREADS

// order-preserving float->u32 (ascending)
__device__ __forceinline__ u32 f2u(float f) {
    u32 b = __float_as_uint(f);
    return (b & 0x80000000u) ? ~b : (b | 0x80000000u);
}
__device__ __forceinline__ float u2f(u32 u) {
    u32 b = (u & 0x80000000u) ? (u ^ 0x80000000u) : ~u;
    return __uint_as_float(b);
}
__device__ __forceinline__ int bucketOf(float v) {   // exact monotone (pow2 scale)
    int b = (int)floorf(v * (float)NB);
    return min(max(b, 0), NB - 1);
}

// decode + write one winner at output slot `rank` of batch b
__device__ __forceinline__ void decode_write(int b, int rank, float score, int cls, int ridx,
                                             const float* __restrict__ rot_sine,
                                             const float* __restrict__ rot_cosine,
                                             const float* __restrict__ hei,
                                             const float* __restrict__ dim,
                                             const float* __restrict__ vel,
                                             const float* __restrict__ reg,
                                             float* __restrict__ out) {
    float xs = (float)(ridx % WW);
    float ys = (float)(ridx / WW);
    size_t base = (size_t)b * HW;
    float r0 = reg[((size_t)(b * 2 + 0)) * HW + ridx];
    float r1 = reg[((size_t)(b * 2 + 1)) * HW + ridx];
    float rs = rot_sine[base + ridx];
    float rc = rot_cosine[base + ridx];
    float hg = hei[base + ridx];
    float d0 = dim[((size_t)(b * 3 + 0)) * HW + ridx];
    float d1 = dim[((size_t)(b * 3 + 1)) * HW + ridx];
    float d2 = dim[((size_t)(b * 3 + 2)) * HW + ridx];
    float v0 = vel[((size_t)(b * 2 + 0)) * HW + ridx];
    float v1 = vel[((size_t)(b * 2 + 1)) * HW + ridx];

    float x = (xs + r0) * 0.8f + (-51.2f);
    float y = (ys + r1) * 0.8f + (-51.2f);
    float rot = atan2f(rs, rc);

    size_t obase = ((size_t)b * KSEL + rank) * 9;
    out[obase + 0] = x;
    out[obase + 1] = y;
    out[obase + 2] = hg;
    out[obase + 3] = d0;
    out[obase + 4] = d1;
    out[obase + 5] = d2;
    out[obase + 6] = rot;
    out[obase + 7] = v0;
    out[obase + 8] = v1;

    const int NOUT = BB * KSEL;              // 4000
    out[9 * NOUT + b * KSEL + rank] = score;
    out[10 * NOUT + b * KSEL + rank] = (float)cls;
    bool keep = (x >= -61.2f) && (y >= -61.2f) && (hg >= -10.0f) &&
                (x <= 61.2f) && (y <= 61.2f) && (hg <= 10.0f) &&
                (score > 0.1f);
    out[11 * NOUT + b * KSEL + rank] = keep ? 1.0f : 0.0f;
}

// ---- fallback helpers (256 threads, never taken for this data) ----
__device__ __forceinline__ int find_b1_256(u32* h, u32* ps0, u32* ps1, int* b1_s) {
    const int tid = threadIdx.x;
    u32 p = 0;
#pragma unroll
    for (int q = 0; q < NBQ; ++q) p += h[tid * NBQ + q];
    ps0[tid] = p;
    __syncthreads();
    u32* src = ps0;
    u32* dst = ps1;
    for (int off = 1; off < THREADS; off <<= 1) {    // suffix scan
        u32 v = src[tid] + ((tid + off < THREADS) ? src[tid + off] : 0);
        dst[tid] = v;
        __syncthreads();
        u32* t = src; src = dst; dst = t;
    }
    u32 S_t = src[tid];
    u32 S_next = (tid < THREADS - 1) ? src[tid + 1] : 0;
    if (S_t >= KSEL && (tid == THREADS - 1 || S_next < KSEL)) {
        u32 run = (tid == THREADS - 1) ? 0u : S_next;
        int b1 = tid * NBQ;
        for (int q = NBQ - 1; q >= 0; --q) {
            run += h[tid * NBQ + q];
            if (run >= KSEL) { b1 = tid * NBQ + q; break; }
        }
        *b1_s = b1;
    }
    __syncthreads();
    return *b1_s;
}

__device__ __forceinline__ void bitonic_sort_desc_g(u64* cand) {   // global-memory bitonic
    const int tid = threadIdx.x;
    for (int k2 = 2; k2 <= CANDCAP; k2 <<= 1) {
        for (int j = k2 >> 1; j > 0; j >>= 1) {
            for (int i = tid; i < CANDCAP; i += THREADS) {
                int ixj = i ^ j;
                if (ixj > i) {
                    u64 a = cand[i], b2 = cand[ixj];
                    bool up = ((i & k2) == 0);
                    if ((a < b2) == up) { cand[i] = b2; cand[ixj] = a; }
                }
            }
            __syncthreads();
        }
    }
}

// ---------------- single fused kernel ----------------
__global__ __launch_bounds__(THREADS, 4) void k_fused(
        const float* __restrict__ heat,
        const float* __restrict__ rot_sine,
        const float* __restrict__ rot_cosine,
        const float* __restrict__ hei,
        const float* __restrict__ dim,
        const float* __restrict__ vel,
        const float* __restrict__ reg,
        u32* __restrict__ done,
        u32* __restrict__ cnts,
        u64* __restrict__ prebuf,
        u64* __restrict__ gcand,
        u64* __restrict__ gs1k,
        float* __restrict__ out) {
    const int wg = blockIdx.x;
    const int tid = threadIdx.x;

    __shared__ u64 lbuf[LCAP];
    __shared__ u32 lcnt;
    __shared__ u32 base_s;
    __shared__ u64 keys[CANDCAP];               // 16 KB (reused as fallback hist)
    __shared__ u32 cc[WPB], sc[WPB];
    __shared__ u32 ps0[THREADS], ps1[THREADS];
    __shared__ int fb_s;
    __shared__ int b1_s;
    __shared__ int cnt_s;

    // ---- phase 1: scan my slice of heat ----
    if (tid == 0) {
        lcnt = 0;
        base_s = __hip_atomic_load(done, __ATOMIC_RELAXED, __HIP_MEMORY_SCOPE_AGENT);
    }
    __syncthreads();

    const size_t e_base = (size_t)wg * EPW;
    const float4* hp = (const float4*)(heat + e_base);
#pragma unroll 1
    for (int o = 0; o < 2; ++o) {
#pragma unroll
        for (int i = 0; i < 10; ++i) {
            int f4 = (o * 10 + i) * THREADS + tid;
            float4 v = hp[f4];
            float m = fmaxf(fmaxf(v.x, v.y), fmaxf(v.z, v.w));
            if (m > THRV) {                      // rare (~1 in 600 float4s)
                int e0 = (int)(e_base + (size_t)f4 * 4);
                float vv[4] = {v.x, v.y, v.z, v.w};
#pragma unroll
                for (int j = 0; j < 4; ++j) {
                    if (vv[j] > THRV) {
                        u32 pos = atomicAdd(&lcnt, 1u);
                        if (pos < LCAP) {
                            int e = e0 + j;
                            int bc = e >> 18;
                            int c = bc % CAT;
                            int idx = e & (HW - 1);
                            u32 combo = ((u32)c << 18) | (u32)idx;
                            lbuf[pos] = ((u64)f2u(vv[j]) << 32) | (u32)(0x3FFFFFu - combo);
                        }
                    }
                }
            }
        }
    }
    __syncthreads();
    u32 nmine = lcnt;
    if (tid < LCAP && (u32)tid < nmine) prebuf[(size_t)wg * LCAP + tid] = lbuf[tid];
    if (tid == 0) cnts[wg] = nmine;             // >LCAP signals overflow -> fallback
    __syncthreads();
    if (tid == 0) {
        __threadfence();
        __hip_atomic_fetch_add(done, 1u, __ATOMIC_RELEASE, __HIP_MEMORY_SCOPE_AGENT);
    }
    if (wg >= RANKERS) return;                  // scanners done

    // ---- phase 2 (first 128 WGs): wait for all scans (epoch barrier) ----
    const int b = wg >> 4;                      // batch
    const int slice = wg & (SLICES - 1);
    if (tid == 0) {
        u32 target = (base_s & ~(u32)(NWG - 1)) + NWG;   // modular epoch target
        int iters = 0;
        int bail = 0;
        while ((i32)(__hip_atomic_load(done, __ATOMIC_ACQUIRE, __HIP_MEMORY_SCOPE_AGENT)
                     - target) < 0) {
            __builtin_amdgcn_s_sleep(2);
            if (++iters > (1 << 20)) { bail = 1; break; }   // ~150ms safety net
        }
        fb_s = bail ? 2 : 0;
    }
    __syncthreads();
    __threadfence();

    // ---- phase 3: load counts, prefix-scan, validate ----
    if (fb_s == 0) {
        if (tid < WPB) {
            u32 v = cnts[b * WPB + tid];
            cc[tid] = v;
            if (v > LCAP) fb_s = 1;             // same-value race OK
        }
    }
    __syncthreads();
    if (fb_s == 0) {
        if (tid < WPB) sc[tid] = cc[tid];
        __syncthreads();
        for (int off = 1; off < WPB; off <<= 1) {
            u32 v = 0;
            if (tid < WPB) v = sc[tid] + ((tid >= off) ? sc[tid - off] : 0);
            __syncthreads();
            if (tid < WPB) sc[tid] = v;
            __syncthreads();
        }
        u32 tot0 = sc[WPB - 1];
        if (tid == 0 && (tot0 < KSEL || tot0 > CANDCAP)) fb_s = 1;
        __syncthreads();
    }

    if (fb_s == 0) {
        // ---- fast path: gather keys, rank-count, decode ----
        u32 tot = sc[WPB - 1];
        const int wave = tid >> 6, lane = tid & 63;
        for (int r = wave; r < WPB; r += 4) {
            u32 nr = cc[r];
            u32 off = sc[r] - nr;
            if ((u32)lane < nr)
                keys[off + lane] = prebuf[(size_t)(b * WPB + r) * LCAP + lane];
        }
        for (int i = (int)tot + tid; i < CANDCAP; i += THREADS) keys[i] = 0;
        __syncthreads();

        int ci = slice * 128 + (tid >> 1);      // 128 candidates per slice
        int sub = tid & 1;
        u64 mk = keys[ci];
        u32 q = (tot + 1) >> 1;
        u32 j0 = (u32)sub * q;
        u32 j1 = min(j0 + q, tot);
        u32 r = 0;
#pragma unroll 4
        for (u32 j = j0; j < j1; ++j) r += (keys[j] > mk);   // LDS broadcast reads
        r += __shfl_xor(r, 1);
        if (sub == 0 && ci < (int)tot && r < KSEL) {
            float score = u2f((u32)(mk >> 32));
            u32 combo = 0x3FFFFFu - (u32)(mk & 0xFFFFFFFFull);
            int cls = (int)(combo >> 18);
            int ridx = (int)(combo & 0x3FFFFu);
            decode_write(b, (int)r, score, cls, ridx,
                         rot_sine, rot_cosine, hei, dim, vel, reg, out);
        }
        return;
    }

    // ---- exact fallback: re-scan heat for this batch (never taken; self-sufficient) ----
    if (slice != 0) return;                     // WG-uniform
    u32* h = (u32*)keys;                        // reuse 16 KB LDS as histogram
    u64* cand = gcand + (size_t)b * CANDCAP;
    u64* s1k  = gs1k + (size_t)b * (CAT * KSEL);

    for (int c = 0; c < CAT; ++c) {
        const float* hp2 = heat + (size_t)(b * CAT + c) * HW;
        for (int i = tid; i < NB; i += THREADS) h[i] = 0;
        if (tid == 0) cnt_s = 0;
        __syncthreads();
        for (int i = tid; i < HW; i += THREADS) atomicAdd(&h[bucketOf(hp2[i])], 1u);
        __syncthreads();
        int b1 = find_b1_256(h, ps0, ps1, &b1_s);
        for (int i = tid; i < HW; i += THREADS) {
            float v = hp2[i];
            if (bucketOf(v) >= b1) {
                int pos = atomicAdd(&cnt_s, 1);
                if (pos < CANDCAP)
                    cand[pos] = ((u64)f2u(v) << 32) | (u32)(~(u32)i);
            }
        }
        __syncthreads();
        int c2 = min(cnt_s, CANDCAP);
        for (int i = c2 + tid; i < CANDCAP; i += THREADS) cand[i] = 0;
        __syncthreads();
        bitonic_sort_desc_g(cand);
        for (int r2 = tid; r2 < KSEL; r2 += THREADS) s1k[c * KSEL + r2] = cand[r2];
        __syncthreads();
    }
    const int NCAND = CAT * KSEL;
    for (int i = tid; i < NB; i += THREADS) h[i] = 0;
    if (tid == 0) cnt_s = 0;
    __syncthreads();
    for (int i = tid; i < NCAND; i += THREADS)
        atomicAdd(&h[bucketOf(u2f((u32)(s1k[i] >> 32)))], 1u);
    __syncthreads();
    int b1 = find_b1_256(h, ps0, ps1, &b1_s);
    for (int i = tid; i < NCAND; i += THREADS) {
        u64 k1 = s1k[i];
        float v = u2f((u32)(k1 >> 32));
        if (bucketOf(v) >= b1) {
            int pos = atomicAdd(&cnt_s, 1);
            if (pos < CANDCAP)
                cand[pos] = (k1 & 0xFFFFFFFF00000000ull) | (u32)(~(u32)i);
        }
    }
    __syncthreads();
    int c2 = min(cnt_s, CANDCAP);
    for (int i = c2 + tid; i < CANDCAP; i += THREADS) cand[i] = 0;
    __syncthreads();
    bitonic_sort_desc_g(cand);
    for (int r2 = tid; r2 < KSEL; r2 += THREADS) {
        u64 kk = cand[r2];
        float score = u2f((u32)(kk >> 32));
        int flat = (int)(~(u32)kk);
        int cls = flat / KSEL;
        int ridx = (int)(~(u32)s1k[flat]);
        decode_write(b, r2, score, cls, ridx,
                     rot_sine, rot_cosine, hei, dim, vel, reg, out);
    }
}

extern "C" void kernel_launch(void* const* d_in, const int* in_sizes, int n_in,
                              void* d_out, int out_size, void* d_ws, size_t ws_size,
                              hipStream_t stream) {
    const float* heat       = (const float*)d_in[0];
    const float* rot_sine   = (const float*)d_in[1];
    const float* rot_cosine = (const float*)d_in[2];
    const float* hei        = (const float*)d_in[3];
    const float* dim        = (const float*)d_in[4];
    const float* vel        = (const float*)d_in[5];
    const float* reg        = (const float*)d_in[6];

    char* ws = (char*)d_ws;
    // layout (no zeroing needed anywhere):
    // done    u32   @ 0        (monotonic epoch counter; any initial value OK)
    // cnts    u32[1024]        @ 1024
    // prebuf  u64[1024*48]     @ 8192    (393216 B)
    // gcand   u64[8*2048]      @ 401408  (131072 B, fallback only)
    // gs1k    u64[8*5000]      @ 532480  (320000 B, fallback only)
    u32* done   = (u32*)ws;
    u32* cnts   = (u32*)(ws + 1024);
    u64* prebuf = (u64*)(ws + 8192);
    u64* gcand  = (u64*)(ws + 401408);
    u64* gs1k   = (u64*)(ws + 532480);

    k_fused<<<dim3(NWG), THREADS, 0, stream>>>(heat, rot_sine, rot_cosine, hei, dim, vel, reg,
                                               done, cnts, prebuf, gcand, gs1k,
                                               (float*)d_out);
}